// Round 1
// baseline (128.022 us; speedup 1.0000x reference)
//
#include <hip/hip_runtime.h>
#include <hip/hip_bf16.h>
#include <math.h>

// Problem dims (fixed): B=8, T=1048576, V=257, E=8, C=128, K=512, S=512, N=64
// GEMM view: M = B*L = 8*2048 = 16384, Kdim = E*K = 4096, Ncols = 2*C = 256
#define M_TOT   16384
#define N_TOT   256
#define K_TOT   4096

typedef __bf16 bf16x8 __attribute__((ext_vector_type(8)));
typedef float  f32x4  __attribute__((ext_vector_type(4)));

// ---------------- ws layout ----------------
// [0, 2MB)          : Wp_tiled bf16 [nt=4][s=16][t=8][q=4][n=64][e=8]
// [2MB, 2MB+8KB)    : emb bf16 [257][8] (16B rows)
// [4MB, 20MB)       : Cbuf fp32 [16384][256]
#define WS_WP_OFF   0
#define WS_EMB_OFF  (2u << 20)
#define WS_C_OFF    (4u << 20)

__device__ __forceinline__ void load_lds16(const void* g, void* l) {
    __builtin_amdgcn_global_load_lds(
        (const __attribute__((address_space(1))) void*)g,
        (__attribute__((address_space(3))) void*)l,
        16, 0, 0);
}

// ---------------------------------------------------------------------------
// Kernel 1: pack weights (fp32 -> bf16, MFMA-tiled + k-permuted) and emb table
// dst element u: e = u&7, n = (u>>3)&63, q = (u>>9)&3, t = (u>>11)&7,
//                s = (u>>14)&15, nt = u>>18
// channel c = nt*64+n ; logical byte = s*32 + q*8 + t ; elem = e
// value = (c<128 ? w1 : w2)[(c&127)][e][byte]
// ---------------------------------------------------------------------------
__global__ void prep_kernel(const float* __restrict__ w1,
                            const float* __restrict__ w2,
                            const float* __restrict__ emb,
                            __bf16* __restrict__ Wp,
                            __bf16* __restrict__ embp) {
    int bid = blockIdx.x;
    if (bid < 4096) {
        int u  = bid * 256 + (int)threadIdx.x;     // [0, 1048576)
        int e  = u & 7;
        int n  = (u >> 3) & 63;
        int q  = (u >> 9) & 3;
        int t  = (u >> 11) & 7;
        int s  = (u >> 14) & 15;
        int nt = u >> 18;
        int c  = (nt << 6) | n;
        int byte = (s << 5) | (q << 3) | t;
        float v;
        if (c < 128) v = w1[(c << 12) + (e << 9) + byte];
        else         v = w2[((c - 128) << 12) + (e << 9) + byte];
        Wp[u] = (__bf16)v;
    } else {
        // emb: 257*8 = 2056 fp32 -> bf16
        for (int i = threadIdx.x; i < 2056; i += 256)
            embp[i] = (__bf16)emb[i];
    }
}

// ---------------------------------------------------------------------------
// Kernel 2: GEMM  C[16384][256] = A(emb[x]) @ Wp
// block: 256 thr = 4 waves; BM=128, BN=64; wave-tile 32x64 (2 rg x 4 nf)
// grid: 512 = (M/128=128) x (N/64=4)
// K-superstep = 256 hw-k = 32 bytes; 16 supersteps.
// hw_k_local = t*32 + q*8 + e  <->  byte = s*32 + q*8 + t, elem e
//   => A-frag for step t = emb row of byte (s*32 + q*8 + t); lane's 8 bytes
//      per superstep are x[row*512 + s*32 + q*8 .. +7] (two int4 loads).
// ---------------------------------------------------------------------------
__global__ __launch_bounds__(256, 2)
void gemm_kernel(const int* __restrict__ x,
                 const __bf16* __restrict__ Wp,
                 const uint4* __restrict__ embp,
                 float* __restrict__ Cbuf) {
    __shared__ uint4 ldsB[2048];   // 32 KB: [t=8][q=4][n=64] 16B slots
    __shared__ uint4 embl[260];    // emb table, 16B rows

    const int tid  = threadIdx.x;
    const int wave = tid >> 6;
    const int lane = tid & 63;
    const int q    = lane >> 4;
    const int nl   = lane & 15;

    // stage emb table into LDS (visible after first __syncthreads below)
    for (int i = tid; i < 257; i += 256) embl[i] = embp[i];

    const int nt = blockIdx.x & 3;
    const int mt = blockIdx.x >> 2;
    const int m0 = mt << 7;

    const int rowA0 = m0 + (wave << 5) + nl;       // rg=0 row for this lane
    const long xbase0 = (long)rowA0 * 512 + (q << 3);
    const long xbase1 = xbase0 + 16 * 512;         // rg=1: +16 rows

    const char* WpBase = (const char*)Wp + ((size_t)nt << 15) * 16; // nt*16 chunks * 32KB

    f32x4 acc[2][4] = {};

    for (int s = 0; s < 16; ++s) {
        // per-lane byte indices for this superstep (registers, contiguous)
        const int* xp0 = x + xbase0 + (s << 5);
        const int* xp1 = x + xbase1 + (s << 5);
        int4 i0a = *(const int4*)xp0;
        int4 i0b = *(const int4*)(xp0 + 4);
        int4 i1a = *(const int4*)xp1;
        int4 i1b = *(const int4*)(xp1 + 4);

        // stage B chunk (32 KB) via async global->LDS, width 16
        {
            const char* src = WpBase + ((size_t)s << 15) + tid * 16;
            char* dst = (char*)ldsB + tid * 16;
#pragma unroll
            for (int i = 0; i < 8; ++i)
                load_lds16(src + i * 4096, dst + i * 4096);
        }
        __syncthreads();

        int idx0[8] = {i0a.x, i0a.y, i0a.z, i0a.w, i0b.x, i0b.y, i0b.z, i0b.w};
        int idx1[8] = {i1a.x, i1a.y, i1a.z, i1a.w, i1b.x, i1b.y, i1b.z, i1b.w};

#pragma unroll
        for (int t = 0; t < 8; ++t) {
            bf16x8 a0 = *reinterpret_cast<const bf16x8*>(&embl[idx0[t]]);
            bf16x8 a1 = *reinterpret_cast<const bf16x8*>(&embl[idx1[t]]);
#pragma unroll
            for (int nf = 0; nf < 4; ++nf) {
                bf16x8 b = *reinterpret_cast<const bf16x8*>(
                    (const char*)ldsB + (t << 12) + (q << 10) + (nf << 8) + (nl << 4));
                acc[0][nf] = __builtin_amdgcn_mfma_f32_16x16x32_bf16(a0, b, acc[0][nf], 0, 0, 0);
                acc[1][nf] = __builtin_amdgcn_mfma_f32_16x16x32_bf16(a1, b, acc[1][nf], 0, 0, 0);
            }
        }
        __syncthreads();
    }

    // epilogue: C/D layout col = lane&15, row = q*4 + i
#pragma unroll
    for (int rg = 0; rg < 2; ++rg) {
        int rowbase = m0 + (wave << 5) + (rg << 4) + (q << 2);
#pragma unroll
        for (int nf = 0; nf < 4; ++nf) {
            int col = (nt << 6) + (nf << 4) + nl;
#pragma unroll
            for (int i = 0; i < 4; ++i)
                Cbuf[(size_t)(rowbase + i) * 256 + col] = acc[rg][nf][i];
        }
    }
}

// ---------------------------------------------------------------------------
// Kernel 3: gated activation + per-patch max
// out[b][p][c] = max_{l<32} (C[m][c]+b1[c]) * sigmoid(C[m][c+128]+b2[c]),
//   m = (b*64+p)*32 + l
// grid 256, block 256: each block handles 2 patches (tid>>7), c = tid&127
// ---------------------------------------------------------------------------
__global__ void reduce_kernel(const float* __restrict__ Cbuf,
                              const float* __restrict__ b1,
                              const float* __restrict__ b2,
                              float* __restrict__ out) {
    int tid  = threadIdx.x;
    int c    = tid & 127;
    int gp   = blockIdx.x * 2 + (tid >> 7);   // global patch id [0, 512)
    long mbase = (long)gp << 5;
    float bb1 = b1[c], bb2 = b2[c];
    float best = -INFINITY;
    const float* rowp = Cbuf + mbase * 256 + c;
#pragma unroll 4
    for (int l = 0; l < 32; ++l) {
        float c1 = rowp[0]   + bb1;
        float c2 = rowp[128] + bb2;
        float g  = c1 * (1.0f / (1.0f + __expf(-c2)));
        best = fmaxf(best, g);
        rowp += 256;
    }
    out[(size_t)gp * 128 + c] = best;
}

// ---------------------------------------------------------------------------
extern "C" void kernel_launch(void* const* d_in, const int* in_sizes, int n_in,
                              void* d_out, int out_size, void* d_ws, size_t ws_size,
                              hipStream_t stream) {
    const int*   x   = (const int*)d_in[0];
    const float* emb = (const float*)d_in[1];
    const float* w1  = (const float*)d_in[2];
    const float* b1  = (const float*)d_in[3];
    const float* w2  = (const float*)d_in[4];
    const float* b2  = (const float*)d_in[5];
    float* out = (float*)d_out;

    char* ws = (char*)d_ws;
    __bf16* Wp    = (__bf16*)(ws + WS_WP_OFF);
    __bf16* embp  = (__bf16*)(ws + WS_EMB_OFF);
    float*  Cbuf  = (float*)(ws + WS_C_OFF);

    prep_kernel<<<4097, 256, 0, stream>>>(w1, w2, emb, Wp, embp);
    gemm_kernel<<<512, 256, 0, stream>>>(x, Wp, (const uint4*)embp, Cbuf);
    reduce_kernel<<<256, 256, 0, stream>>>(Cbuf, b1, b2, out);
}

// Round 2
// 124.000 us; speedup vs baseline: 1.0324x; 1.0324x over previous
//
#include <hip/hip_runtime.h>
#include <hip/hip_bf16.h>
#include <math.h>

// Dims: B=8, T=1048576, V=257, E=8, C=128, K=512, S=512, N=64
// GEMM view: M=16384, Kdim=4096, Ncols=256 (w1 cols 0-127, w2 cols 128-255)

typedef __bf16 bf16x8 __attribute__((ext_vector_type(8)));
typedef float  f32x4  __attribute__((ext_vector_type(4)));

// ---------------- ws layout ----------------
// [0, 2MB)    : Wp bf16 [nt=4][s'=16][t=8][q=4][n=64][e=8]  (byte = s'*32+q*8+t)
// [2MB, +8KB) : emb bf16 [257][8]
// [4MB, 20MB) : Cbuf kh=0 fp32 [16384][256]
// [20MB,36MB) : Cbuf kh=1 (only if ksplit==2)
#define WS_WP_OFF   0
#define WS_EMB_OFF  (2u << 20)
#define WS_C_OFF    (4u << 20)

__device__ __forceinline__ void load_lds16(const void* g, void* l) {
    __builtin_amdgcn_global_load_lds(
        (const __attribute__((address_space(1))) void*)g,
        (__attribute__((address_space(3))) void*)l,
        16, 0, 0);
}

// ---------------------------------------------------------------------------
// prep: coalesced LDS-transpose weight pack + emb bf16 table
// block (bid<128): cb=bid&7 (32 channels), sB=bid>>3 (byte block of 32)
// reads 128B-contiguous segments, writes 512B-contiguous uint4 runs
// ---------------------------------------------------------------------------
__global__ void prep_kernel(const float* __restrict__ w1,
                            const float* __restrict__ w2,
                            const float* __restrict__ emb,
                            uint4* __restrict__ Wp4,
                            __bf16* __restrict__ embp) {
    int bid = blockIdx.x;
    int tid = threadIdx.x;
    if (bid < 128) {
        __shared__ __bf16 lds[8192];   // [(q*8+t)*32 + cl]*8 + e
        int cb = bid & 7;
        int sB = bid >> 3;
        int c0 = cb << 5;
        const float* wsrc = (c0 < 128) ? (w1 + ((size_t)c0 << 12))
                                       : (w2 + ((size_t)(c0 - 128) << 12));
        int j4  = tid & 7;
        int pr0 = tid >> 3;
#pragma unroll
        for (int p = 0; p < 8; ++p) {
            int pair = p * 32 + pr0;          // 0..255 = (cl, e)
            int cl = pair >> 3, e = pair & 7;
            const float4 v = *(const float4*)(wsrc + (cl << 12) + (e << 9) + (sB << 5) + (j4 << 2));
            float vv[4] = {v.x, v.y, v.z, v.w};
#pragma unroll
            for (int jj = 0; jj < 4; ++jj) {
                int j = (j4 << 2) + jj;        // byte_local
                int qq = j >> 3, tt = j & 7;
                lds[(((qq << 3) + tt) * 32 + cl) * 8 + e] = (__bf16)vv[jj];
            }
        }
        __syncthreads();
        const uint4* l4 = (const uint4*)lds;
        int nhalf = cb & 1, nt = cb >> 1;
        int base = (nt << 15) + (sB << 11) + (nhalf << 5);   // uint4 units
#pragma unroll
        for (int it = 0; it < 4; ++it) {
            int idx = it * 256 + tid;                         // 0..1023
            int qq = idx >> 8, tt = (idx >> 5) & 7, w = idx & 31;
            Wp4[base + (tt << 8) + (qq << 6) + w] = l4[idx];
        }
    } else {
        for (int i = tid; i < 2056; i += 256) embp[i] = (__bf16)emb[i];
    }
}

// ---------------------------------------------------------------------------
// gemm: BM=256, BN=64, 4 waves, wave-tile 64x64 (4rg x 4nf), K-split ksplit
// double-buffered B staging (global_load_lds w=16), x-idx prefetch, emb in LDS
// ---------------------------------------------------------------------------
__global__ __launch_bounds__(256, 2)
void gemm_kernel(const int* __restrict__ x,
                 const __bf16* __restrict__ Wp,
                 const uint4* __restrict__ embp,
                 float* __restrict__ Cbuf,
                 int ksplit) {
    __shared__ uint4 ldsB[2][2048];   // 2 x 32KB: [t=8][q=4][n=64][e=8]
    __shared__ uint4 embl[257];

    const int tid  = threadIdx.x;
    const int wave = tid >> 6;
    const int lane = tid & 63;
    const int q    = lane >> 4;
    const int nl   = lane & 15;

    for (int i = tid; i < 257; i += 256) embl[i] = embp[i];

    const int bid = blockIdx.x;
    int mt, nt, kh, nsteps, s0;
    if (ksplit == 2) {
        mt = ((bid >> 6) << 3) | (bid & 7);     // same-XCD blocks share mt
        int combo = (bid >> 3) & 7;
        kh = combo & 1; nt = combo >> 1;
        nsteps = 8; s0 = kh << 3;
    } else {
        mt = ((bid >> 5) << 3) | (bid & 7);
        nt = (bid >> 3) & 3;
        kh = 0; nsteps = 16; s0 = 0;
    }
    const int m0 = mt << 8;
    const int rA = m0 + (wave << 6) + nl;
    const char* WpBase = (const char*)Wp + ((size_t)nt << 19);

    const int* xp[4];
#pragma unroll
    for (int rg = 0; rg < 4; ++rg)
        xp[rg] = x + (size_t)(rA + (rg << 4)) * 512 + (q << 3);

    int4 xc[4][2];
#pragma unroll
    for (int rg = 0; rg < 4; ++rg) {
        const int* p = xp[rg] + (s0 << 5);
        xc[rg][0] = *(const int4*)p;
        xc[rg][1] = *(const int4*)(p + 4);
    }
    {
        const char* src = WpBase + ((size_t)s0 << 15) + tid * 16;
        char* dst = (char*)&ldsB[0][0] + tid * 16;
#pragma unroll
        for (int i = 0; i < 8; ++i) load_lds16(src + i * 4096, dst + i * 4096);
    }
    __syncthreads();

    f32x4 acc[4][4] = {};

    for (int ss = 0; ss < nsteps; ++ss) {
        const int sp  = s0 + ss;
        const int buf = ss & 1;
        if (ss + 1 < nsteps) {   // stage next step into other buffer (async)
            const char* src = WpBase + ((size_t)(sp + 1) << 15) + tid * 16;
            char* dst = (char*)&ldsB[buf ^ 1][0] + tid * 16;
#pragma unroll
            for (int i = 0; i < 8; ++i) load_lds16(src + i * 4096, dst + i * 4096);
        }
        int idx[4][8];
#pragma unroll
        for (int rg = 0; rg < 4; ++rg) {
            idx[rg][0] = xc[rg][0].x; idx[rg][1] = xc[rg][0].y;
            idx[rg][2] = xc[rg][0].z; idx[rg][3] = xc[rg][0].w;
            idx[rg][4] = xc[rg][1].x; idx[rg][5] = xc[rg][1].y;
            idx[rg][6] = xc[rg][1].z; idx[rg][7] = xc[rg][1].w;
        }
        const int spn = (ss + 1 < nsteps) ? sp + 1 : sp;   // x prefetch
#pragma unroll
        for (int rg = 0; rg < 4; ++rg) {
            const int* p = xp[rg] + (spn << 5);
            xc[rg][0] = *(const int4*)p;
            xc[rg][1] = *(const int4*)(p + 4);
        }
        const char* Bbase = (const char*)&ldsB[buf][0] + (q << 10) + (nl << 4);
#pragma unroll
        for (int t = 0; t < 8; ++t) {
            bf16x8 a[4];
#pragma unroll
            for (int rg = 0; rg < 4; ++rg)
                a[rg] = *reinterpret_cast<const bf16x8*>(&embl[idx[rg][t]]);
#pragma unroll
            for (int nf = 0; nf < 4; ++nf) {
                bf16x8 b = *reinterpret_cast<const bf16x8*>(Bbase + (t << 12) + (nf << 8));
#pragma unroll
                for (int rg = 0; rg < 4; ++rg)
                    acc[rg][nf] = __builtin_amdgcn_mfma_f32_16x16x32_bf16(a[rg], b, acc[rg][nf], 0, 0, 0);
            }
        }
        __syncthreads();
    }

    float* Cout = Cbuf + (size_t)kh * (16384 * 256);
#pragma unroll
    for (int rg = 0; rg < 4; ++rg) {
        int rowb = m0 + (wave << 6) + (rg << 4) + (q << 2);
#pragma unroll
        for (int nf = 0; nf < 4; ++nf) {
            int col = (nt << 6) + (nf << 4) + nl;
#pragma unroll
            for (int i = 0; i < 4; ++i)
                Cout[(size_t)(rowb + i) * 256 + col] = acc[rg][nf][i];
        }
    }
}

// ---------------------------------------------------------------------------
// reduce: sum K-split partials, bias, gate, per-patch max. 512 blocks.
// block = patch; tid = lh*128 + c; each thread 16 rows, LDS combine.
// ---------------------------------------------------------------------------
__global__ void reduce_kernel(const float* __restrict__ Cbuf,
                              const float* __restrict__ b1,
                              const float* __restrict__ b2,
                              float* __restrict__ out,
                              int ksplit) {
    __shared__ float sm[256];
    int tid = threadIdx.x;
    int c   = tid & 127;
    int lh  = tid >> 7;
    int gp  = blockIdx.x;
    float bb1 = b1[c], bb2 = b2[c];
    const float* base0 = Cbuf + (size_t)(gp * 32 + lh * 16) * 256 + c;
    const float* base1 = base0 + (size_t)16384 * 256;
    const bool ks2 = (ksplit == 2);
    float best = -INFINITY;
#pragma unroll 4
    for (int l = 0; l < 16; ++l) {
        float c1 = base0[0]   + bb1;
        float c2 = base0[128] + bb2;
        if (ks2) { c1 += base1[0]; c2 += base1[128]; }
        float g = c1 * (1.0f / (1.0f + __expf(-c2)));
        best = fmaxf(best, g);
        base0 += 256; base1 += 256;
    }
    sm[tid] = best;
    __syncthreads();
    if (lh == 0) out[(size_t)gp * 128 + c] = fmaxf(sm[tid], sm[tid + 128]);
}

// ---------------------------------------------------------------------------
extern "C" void kernel_launch(void* const* d_in, const int* in_sizes, int n_in,
                              void* d_out, int out_size, void* d_ws, size_t ws_size,
                              hipStream_t stream) {
    const int*   x   = (const int*)d_in[0];
    const float* emb = (const float*)d_in[1];
    const float* w1  = (const float*)d_in[2];
    const float* b1  = (const float*)d_in[3];
    const float* w2  = (const float*)d_in[4];
    const float* b2  = (const float*)d_in[5];
    float* out = (float*)d_out;

    char* ws = (char*)d_ws;
    __bf16* Wp   = (__bf16*)(ws + WS_WP_OFF);
    __bf16* embp = (__bf16*)(ws + WS_EMB_OFF);
    float*  Cbuf = (float*)(ws + WS_C_OFF);

    const size_t need2 = (size_t)(4u << 20) + 2ull * 16384 * 256 * 4;
    int ksplit = (ws_size >= need2) ? 2 : 1;

    prep_kernel<<<129, 256, 0, stream>>>(w1, w2, emb, (uint4*)Wp, embp);
    gemm_kernel<<<256 * ksplit, 256, 0, stream>>>(x, Wp, (const uint4*)embp, Cbuf, ksplit);
    reduce_kernel<<<512, 256, 0, stream>>>(Cbuf, b1, b2, out, ksplit);
}